// Round 11
// baseline (1147.433 us; speedup 1.0000x reference)
//
#include <hip/hip_runtime.h>

#define NN 50000
#define NE 500000
#define DD 128
#define NL 4
#define NG 64
#define FIXED_DIM 10000
#define BN_EPS 1e-5f
#define NB 196   // ceil(NN/256)

typedef unsigned short u16;
typedef unsigned int u32;
typedef __attribute__((ext_vector_type(8))) short bf16x8;
typedef __attribute__((ext_vector_type(4))) float f32x4;

__device__ __forceinline__ float bf2f(u16 u) {
    return __uint_as_float(((u32)u) << 16);
}
__device__ __forceinline__ u16 f2bf(float f) {
    u32 u = __float_as_uint(f);
    return (u16)((u + 0x7FFFu + ((u >> 16) & 1u)) >> 16);
}
// adaptive float-INPUT load (isbf: bf16 vs fp32)
__device__ __forceinline__ float ldf(const void* p, size_t i, int isbf) {
    return isbf ? bf2f(((const u16*)p)[i]) : ((const float*)p)[i];
}

// dtype probe on value_proj_b's first 128 u16 (256 B, in-bounds either way)
__global__ void k_detect(const void* __restrict__ vb, int* __restrict__ flag) {
    __shared__ int ok[128];
    int t = threadIdx.x;
    float v = bf2f(((const u16*)vb)[t]);
    ok[t] = (fabsf(v) < 1000.f) ? 1 : 0;   // NaN -> 0
    __syncthreads();
    for (int off = 64; off; off >>= 1) {
        if (t < off) ok[t] &= ok[t + off];
        __syncthreads();
    }
    if (t == 0) *flag = ok[0];             // 1 = bf16 inputs, 0 = fp32
}

__global__ void k_zero(float* __restrict__ p, int n) {
    int i = blockIdx.x * 256 + threadIdx.x;
    if (i < n) p[i] = 0.0f;
}
// convert 6 per-layer param tensors (each NL*DD) into one fp32 block
__global__ void k_cvt6(const void* b1, const void* b2, const void* g1,
                       const void* be1, const void* g2, const void* be2,
                       float* __restrict__ pc, const int* __restrict__ flag) {
    int t = blockIdx.x * 256 + threadIdx.x;
    if (t >= 6 * NL * DD) return;
    int p = t >> 9, j = t & 511;
    const void* s = (p == 0) ? b1 : (p == 1) ? b2 : (p == 2) ? g1
                  : (p == 3) ? be1 : (p == 4) ? g2 : be2;
    pc[t] = ldf(s, j, *flag);
}
__global__ void k_deg(const int* __restrict__ dst, int* __restrict__ deg) {
    int i = blockIdx.x * 256 + threadIdx.x;
    if (i < NE) atomicAdd(&deg[dst[i]], 1);
}
// batch is sorted: goff[g] = lower_bound(batch, g); goff[NG] = NN
__global__ void k_goff(const int* __restrict__ batch, int* __restrict__ goff) {
    int g = threadIdx.x;
    if (g > NG) return;
    int lo = 0, hi = NN;
    while (lo < hi) {
        int mid = (lo + hi) >> 1;
        if (batch[mid] < g) lo = mid + 1; else hi = mid;
    }
    goff[g] = lo;
}

// ---- parallel exclusive scan of deg -> rowptr (3 stages) ----
__global__ void k_scan1(const int* __restrict__ deg, int* __restrict__ bsum) {
    __shared__ int S[256];
    int b = blockIdx.x, t = threadIdx.x;
    int i = b * 256 + t;
    S[t] = (i < NN) ? deg[i] : 0;
    __syncthreads();
    for (int off = 128; off; off >>= 1) {
        if (t < off) S[t] += S[t + off];
        __syncthreads();
    }
    if (t == 0) bsum[b] = S[0];
}
__global__ void k_scan2(int* __restrict__ bsum) {   // 1 block, 256 thr
    __shared__ int S[256];
    int t = threadIdx.x;
    int v = (t < NB) ? bsum[t] : 0;
    S[t] = v;
    __syncthreads();
    for (int off = 1; off < 256; off <<= 1) {
        int x = (t >= off) ? S[t - off] : 0;
        __syncthreads();
        S[t] += x;
        __syncthreads();
    }
    if (t < NB) bsum[t] = S[t] - v;                 // exclusive
}
__global__ void k_scan3(const int* __restrict__ deg, const int* __restrict__ bsum,
                        int* __restrict__ rowptr) {
    __shared__ int S[256];
    int b = blockIdx.x, t = threadIdx.x;
    int i = b * 256 + t;
    int v = (i < NN) ? deg[i] : 0;
    S[t] = v;
    __syncthreads();
    for (int off = 1; off < 256; off <<= 1) {
        int x = (t >= off) ? S[t - off] : 0;
        __syncthreads();
        S[t] += x;
        __syncthreads();
    }
    if (i < NN) rowptr[i] = bsum[b] + S[t] - v;
    if (i == NN - 1) rowptr[NN] = bsum[b] + S[t];   // == NE
}

__global__ void k_fill(const int* __restrict__ src, const int* __restrict__ dst,
                       const int* __restrict__ rowptr, int* __restrict__ cursor,
                       int* __restrict__ colidx) {
    int e = blockIdx.x * 256 + threadIdx.x;
    if (e >= NE) return;
    int d = dst[e];
    int p = atomicAdd(&cursor[d], 1);
    colidx[rowptr[d] + p] = src[e];
}

// pre-swizzle 8 weight matrices into MFMA B-fragment order:
// Wsw[m*16384 + ((nt*4+ks)*64 + lane)*8 + j]
//   = W_m[ks*32 + (lane>>4)*8 + j][nt*16 + (lane&15)]   (bf16)
__global__ void k_swz(const void* __restrict__ w1, const void* __restrict__ w2,
                      u16* __restrict__ Wsw, const int* __restrict__ flag) {
    int t = blockIdx.x * 256 + threadIdx.x;   // 8*16384 = 131072
    if (t >= 8 * 16384) return;
    int m    = t >> 14;
    int idx  = t & 16383;
    int nt   = idx >> 11;
    int ks   = (idx >> 9) & 3;
    int lane = (idx >> 3) & 63;
    int j    = idx & 7;
    int row = ks * 32 + (lane >> 4) * 8 + j;
    int col = nt * 16 + (lane & 15);
    const void* src = (m < 4) ? w1 : w2;
    size_t off = (size_t)(m & 3) * DD * DD + (size_t)row * DD + col;
    Wsw[t] = f2bf(ldf(src, off, *flag));
}

// h0 = vw[feat] + vb + deg_emb[min(deg,1000)] -> B (bf16)
__global__ void k_init(const int* __restrict__ feat, const int* __restrict__ deg,
                       const void* __restrict__ vw, const void* __restrict__ vb,
                       const void* __restrict__ demb, u16* __restrict__ B,
                       const int* __restrict__ flag) {
    int t = blockIdx.x * 256 + threadIdx.x;
    if (t >= NN * DD) return;
    int n = t >> 7, c = t & 127;
    int isbf = *flag;
    int f = feat[n] % FIXED_DIM;
    int dg = min(deg[n], 1000);
    B[t] = f2bf(ldf(vw, (size_t)f * DD + c, isbf)
              + ldf(vb, c, isbf)
              + ldf(demb, (size_t)dg * DD + c, isbf));
}

// ---- fused GIN-aggregate + GEMM1: Out = (sum_nbr f(B)) @ W1 + b1 ----
// f(x) = AFF ? relu(a[c]*x + b[c]) : x  (a,b inline from prev BN2 stats)
// Gather staged per wave (wave = 1 row, lane = 2 cols), bf16 into LDS A-tile,
// then 16x16x32 MFMA; epilogue fuses bias + column stats.
template <bool AFF>
__global__ __launch_bounds__(256, 2) void k_fgemm(
        const u16* __restrict__ B, const int* __restrict__ rowptr,
        const int* __restrict__ colidx, const u16* __restrict__ Wsw,
        const float* __restrict__ bias,
        const float* __restrict__ gIn, const float* __restrict__ bIn,
        const float* __restrict__ sIn, const float* __restrict__ qIn,
        float* __restrict__ Out, float* __restrict__ ssum, float* __restrict__ ssq,
        int nRows) {
    __shared__ u16 Wl[16384];          // 32 KB swizzled W
    __shared__ u16 At[64 * 136];       // 17.4 KB bf16 A-tile, pitch 136
    __shared__ float RedS[4 * 128];
    __shared__ float RedQ[4 * 128];
    __shared__ float affS[256];
    const int t = threadIdx.x;
    const int row0 = blockIdx.x * 64;
    const int w  = t >> 6;
    const int ln = t & 63;

    if (AFF) {
        if (t < 128) {
            float inv = 1.0f / (float)NN;
            float mu = sIn[t] * inv;
            float var = fmaxf(qIn[t] * inv - mu * mu, 0.f);
            float a = gIn[t] * rsqrtf(var + BN_EPS);
            affS[t] = a;
            affS[128 + t] = bIn[t] - a * mu;
        }
        __syncthreads();
    }

    // stage swizzled W: 2048 uint4
    {
        const uint4* s = (const uint4*)Wsw;
        uint4* d = (uint4*)Wl;
        #pragma unroll
        for (int i = 0; i < 8; i++) d[t + i * 256] = s[t + i * 256];
    }

    // gather-stage A-tile: wave w handles rows w*16+rr, lane covers cols c2,c2+1
    {
        const int c2 = ln * 2;
        float a0 = 1.f, b0 = 0.f, a1 = 1.f, b1 = 0.f;
        if (AFF) {
            a0 = affS[c2];       a1 = affS[c2 + 1];
            b0 = affS[128 + c2]; b1 = affS[128 + c2 + 1];
        }
        for (int rr = 0; rr < 16; rr++) {
            int r  = w * 16 + rr;
            int gr = row0 + r;
            float s0 = 0.f, s1 = 0.f;
            if (gr < nRows) {
                u32 wd = *(const u32*)&B[(size_t)gr * DD + c2];
                float x0 = bf2f((u16)(wd & 0xFFFF)), x1 = bf2f((u16)(wd >> 16));
                s0 = AFF ? fmaxf(fmaf(a0, x0, b0), 0.f) : x0;
                s1 = AFF ? fmaxf(fmaf(a1, x1, b1), 0.f) : x1;
                int lo = rowptr[gr], hi = rowptr[gr + 1];
                for (int j = lo; j < hi; j++) {
                    int m = colidx[j];
                    wd = *(const u32*)&B[(size_t)m * DD + c2];
                    x0 = bf2f((u16)(wd & 0xFFFF)); x1 = bf2f((u16)(wd >> 16));
                    s0 += AFF ? fmaxf(fmaf(a0, x0, b0), 0.f) : x0;
                    s1 += AFF ? fmaxf(fmaf(a1, x1, b1), 0.f) : x1;
                }
            }
            u32 packed = ((u32)f2bf(s1) << 16) | (u32)f2bf(s0);
            *(u32*)&At[r * 136 + c2] = packed;
        }
    }
    __syncthreads();

    const int quad = ln >> 4;
    const int lq   = ln & 15;

    f32x4 acc[8];
    #pragma unroll
    for (int nt = 0; nt < 8; nt++) acc[nt] = (f32x4){0.f, 0.f, 0.f, 0.f};

    const u16* aRow = &At[(w * 16 + lq) * 136 + quad * 8];
    #pragma unroll
    for (int ks = 0; ks < 4; ks++) {
        bf16x8 a = *(const bf16x8*)&aRow[ks * 32];
        #pragma unroll
        for (int nt = 0; nt < 8; nt++) {
            bf16x8 b = *(const bf16x8*)&Wl[((nt * 4 + ks) * 64 + ln) * 8];
            acc[nt] = __builtin_amdgcn_mfma_f32_16x16x32_bf16(a, b, acc[nt], 0, 0, 0);
        }
    }

    // epilogue: D[row=quad*4+r][col=nt*16+lq]; +bias, store fp32, fused stats
    const int rbase = row0 + w * 16 + quad * 4;
    #pragma unroll
    for (int nt = 0; nt < 8; nt++) {
        int col = nt * 16 + lq;
        float bv = bias[col];
        float s = 0.f, q = 0.f;
        #pragma unroll
        for (int r = 0; r < 4; r++) {
            int grow = rbase + r;
            if (grow < nRows) {
                float val = acc[nt][r] + bv;
                Out[(size_t)grow * DD + col] = val;
                s += val; q += val * val;
            }
        }
        s += __shfl_xor(s, 16); q += __shfl_xor(q, 16);
        s += __shfl_xor(s, 32); q += __shfl_xor(q, 32);
        if (quad == 0) { RedS[w * 128 + col] = s; RedQ[w * 128 + col] = q; }
    }
    __syncthreads();
    if (t < 128) {
        float s = RedS[t] + RedS[128 + t] + RedS[256 + t] + RedS[384 + t];
        float q = RedQ[t] + RedQ[128 + t] + RedQ[256 + t] + RedQ[384 + t];
        atomicAdd(&ssum[t], s);
        atomicAdd(&ssq[t], q);
    }
}

// ---- GEMM2: Out(bf16) = relu(aff1 * In + b) @ W2 + b2, aff from BN1 stats ----
__global__ __launch_bounds__(256, 2) void k_gemm(
        const float* __restrict__ In, const u16* __restrict__ Wsw,
        const float* __restrict__ bias,
        const float* __restrict__ gIn, const float* __restrict__ bIn,
        const float* __restrict__ sIn, const float* __restrict__ qIn,
        u16* __restrict__ Out, float* __restrict__ ssum, float* __restrict__ ssq,
        int nRows) {
    __shared__ u16 Wl[16384];
    __shared__ u16 At[64 * 136];
    __shared__ float RedS[4 * 128];
    __shared__ float RedQ[4 * 128];
    __shared__ float affS[256];
    const int t = threadIdx.x;
    const int row0 = blockIdx.x * 64;

    if (t < 128) {
        float inv = 1.0f / (float)NN;
        float mu = sIn[t] * inv;
        float var = fmaxf(qIn[t] * inv - mu * mu, 0.f);
        float a = gIn[t] * rsqrtf(var + BN_EPS);
        affS[t] = a;
        affS[128 + t] = bIn[t] - a * mu;
    }
    __syncthreads();

    {
        const uint4* s = (const uint4*)Wsw;
        uint4* d = (uint4*)Wl;
        #pragma unroll
        for (int i = 0; i < 8; i++) d[t + i * 256] = s[t + i * 256];
    }
    for (int i = t; i < 2048; i += 256) {
        int r  = i >> 5;
        int c4 = (i & 31) * 4;
        int gr = row0 + r;
        float4 v = make_float4(0.f, 0.f, 0.f, 0.f);
        if (gr < nRows) {
            v = *(const float4*)&In[(size_t)gr * DD + c4];
            v.x = fmaxf(fmaf(affS[c4 + 0], v.x, affS[128 + c4 + 0]), 0.f);
            v.y = fmaxf(fmaf(affS[c4 + 1], v.y, affS[128 + c4 + 1]), 0.f);
            v.z = fmaxf(fmaf(affS[c4 + 2], v.z, affS[128 + c4 + 2]), 0.f);
            v.w = fmaxf(fmaf(affS[c4 + 3], v.w, affS[128 + c4 + 3]), 0.f);
        }
        ushort4 o;
        o.x = f2bf(v.x); o.y = f2bf(v.y); o.z = f2bf(v.z); o.w = f2bf(v.w);
        *(ushort4*)&At[r * 136 + c4] = o;
    }
    __syncthreads();

    const int w    = t >> 6;
    const int ln   = t & 63;
    const int quad = ln >> 4;
    const int lq   = ln & 15;

    f32x4 acc[8];
    #pragma unroll
    for (int nt = 0; nt < 8; nt++) acc[nt] = (f32x4){0.f, 0.f, 0.f, 0.f};

    const u16* aRow = &At[(w * 16 + lq) * 136 + quad * 8];
    #pragma unroll
    for (int ks = 0; ks < 4; ks++) {
        bf16x8 a = *(const bf16x8*)&aRow[ks * 32];
        #pragma unroll
        for (int nt = 0; nt < 8; nt++) {
            bf16x8 b = *(const bf16x8*)&Wl[((nt * 4 + ks) * 64 + ln) * 8];
            acc[nt] = __builtin_amdgcn_mfma_f32_16x16x32_bf16(a, b, acc[nt], 0, 0, 0);
        }
    }

    const int rbase = row0 + w * 16 + quad * 4;
    #pragma unroll
    for (int nt = 0; nt < 8; nt++) {
        int col = nt * 16 + lq;
        float bv = bias[col];
        float s = 0.f, q = 0.f;
        #pragma unroll
        for (int r = 0; r < 4; r++) {
            int grow = rbase + r;
            if (grow < nRows) {
                float val = acc[nt][r] + bv;
                Out[(size_t)grow * DD + col] = f2bf(val);
                s += val; q += val * val;
            }
        }
        s += __shfl_xor(s, 16); q += __shfl_xor(q, 16);
        s += __shfl_xor(s, 32); q += __shfl_xor(q, 32);
        if (quad == 0) { RedS[w * 128 + col] = s; RedQ[w * 128 + col] = q; }
    }
    __syncthreads();
    if (t < 128) {
        float s = RedS[t] + RedS[128 + t] + RedS[256 + t] + RedS[384 + t];
        float q = RedQ[t] + RedQ[128 + t] + RedQ[256 + t] + RedQ[384 + t];
        atomicAdd(&ssum[t], s);
        atomicAdd(&ssq[t], q);
    }
}

// final h = relu(a*z2+b) -> A (fp32) + segment-accumulated pool partials.
// block = 64 rows x 128 cols; batch sorted -> per-thread segment flush,
// ~1-2 spread atomics per thread.
__global__ __launch_bounds__(256, 4) void k_update2(
        const u16* __restrict__ Bz,
        const float* __restrict__ gIn, const float* __restrict__ bIn,
        const float* __restrict__ sIn, const float* __restrict__ qIn,
        const int* __restrict__ batch, float* __restrict__ A,
        float* __restrict__ gsum) {
    const int t = threadIdx.x;
    const int c = t & 127;
    const int half = t >> 7;           // rows half + 2i
    const int r0 = blockIdx.x * 64;
    float inv = 1.0f / (float)NN;
    float mu = sIn[c] * inv;
    float var = fmaxf(qIn[c] * inv - mu * mu, 0.f);
    float a = gIn[c] * rsqrtf(var + BN_EPS);
    float bb = bIn[c] - a * mu;
    float acc = 0.f;
    int curg = -1;
    for (int i = 0; i < 32; i++) {
        int r = r0 + half + 2 * i;
        if (r >= NN) break;
        int gg = batch[r];
        if (gg != curg) {
            if (curg >= 0) atomicAdd(&gsum[(size_t)curg * DD + c], acc);
            acc = 0.f; curg = gg;
        }
        float v = fmaxf(fmaf(a, bf2f(Bz[(size_t)r * DD + c]), bb), 0.f);
        A[(size_t)r * DD + c] = v;
        acc += v;
    }
    if (curg >= 0) atomicAdd(&gsum[(size_t)curg * DD + c], acc);
}

__global__ void k_pool2(const float* __restrict__ gsum, const int* __restrict__ goff,
                        float* __restrict__ out) {
    int t = blockIdx.x * 256 + threadIdx.x;   // G*DD exact
    int g = t >> 7;
    float cnt = fmaxf((float)(goff[g + 1] - goff[g]), 1.0f);
    out[t] = gsum[t] / cnt;
}

extern "C" void kernel_launch(void* const* d_in, const int* in_sizes, int n_in,
                              void* d_out, int out_size, void* d_ws, size_t ws_size,
                              hipStream_t stream) {
    const int* feat  = (const int*)d_in[0];
    const int* ei    = (const int*)d_in[1];
    const int* batch = (const int*)d_in[2];
    const void* vw   = d_in[3];
    const void* vb   = d_in[4];
    const void* demb = d_in[5];
    const void* w1   = d_in[6];
    const void* b1   = d_in[7];
    const void* g1   = d_in[8];
    const void* be1  = d_in[9];
    const void* w2   = d_in[10];
    const void* b2   = d_in[11];
    const void* g2   = d_in[12];
    const void* be2  = d_in[13];

    const int* src = ei;
    const int* dst = ei + NE;
    const size_t ND = (size_t)NN * DD;

    // ---- workspace layout (~15.6 MB; R5..R10 prove ws >= this) ----
    float* pc     = (float*)d_ws;            // 3072: b1,b2,g1,be1,g2,be2
    int*   flag   = (int*)(pc + 3072);       // 64
    float* stats  = (float*)(flag + 64);     // 2048 [zero from here...]
    float* gsum   = stats + 2048;            // 8192
    int*   deg    = (int*)(gsum + 8192);     // NN
    int*   cursor = deg + NN;                // NN   [...to here]
    int*   bsum   = cursor + NN;             // 256
    int*   goff   = bsum + 256;              // 128 (65 used)
    int*   rowptr = goff + 128;              // NN+64
    int*   colidx = rowptr + NN + 64;        // NE
    u16*   Wsw    = (u16*)(colidx + NE);     // 8*16384 u16
    u16*   B      = Wsw + 8 * 16384;         // ND bf16

    float* b1c  = pc;
    float* b2c  = pc + 512;
    float* g1c  = pc + 1024;
    float* be1c = pc + 1536;
    float* g2c  = pc + 2048;
    float* be2c = pc + 2560;
    float* sum1 = stats;          // [NL][128]
    float* sq1  = stats + 512;
    float* sum2 = stats + 1024;
    float* sq2  = stats + 1536;

    float* outw = (float*)d_out;             // [0, NG*DD): graph_feature
    float* A    = outw + (size_t)NG * DD;    // h region doubles as fp32 buffer A

    const int zwords = 2048 + 8192 + NN + NN;   // stats, gsum, deg, cursor
    const int gridND = (int)((ND + 255) / 256);
    const int gemmBlocks = (NN + 63) / 64;   // 782

    k_detect<<<1, 128, 0, stream>>>(vb, flag);
    k_zero<<<(zwords + 255) / 256, 256, 0, stream>>>(stats, zwords);
    k_cvt6<<<(6 * NL * DD + 255) / 256, 256, 0, stream>>>(b1, b2, g1, be1, g2, be2, pc, flag);
    k_swz<<<(8 * 16384) / 256, 256, 0, stream>>>(w1, w2, Wsw, flag);
    k_deg<<<(NE + 255) / 256, 256, 0, stream>>>(dst, deg);
    k_goff<<<1, 128, 0, stream>>>(batch, goff);
    k_scan1<<<NB, 256, 0, stream>>>(deg, bsum);
    k_scan2<<<1, 256, 0, stream>>>(bsum);
    k_scan3<<<NB, 256, 0, stream>>>(deg, bsum, rowptr);
    k_fill<<<(NE + 255) / 256, 256, 0, stream>>>(src, dst, rowptr, cursor, colidx);
    k_init<<<gridND, 256, 0, stream>>>(feat, deg, vw, vb, demb, B, flag);

    for (int l = 0; l < NL; l++) {
        const u16* W1l = Wsw + (size_t)l * 16384;
        const u16* W2l = Wsw + (size_t)(4 + l) * 16384;
        if (l == 0) {
            k_fgemm<false><<<gemmBlocks, 256, 0, stream>>>(
                B, rowptr, colidx, W1l, b1c + l * 128,
                nullptr, nullptr, nullptr, nullptr,
                A, sum1 + l * 128, sq1 + l * 128, NN);
        } else {
            k_fgemm<true><<<gemmBlocks, 256, 0, stream>>>(
                B, rowptr, colidx, W1l, b1c + l * 128,
                g2c + (l - 1) * 128, be2c + (l - 1) * 128,
                sum2 + (l - 1) * 128, sq2 + (l - 1) * 128,
                A, sum1 + l * 128, sq1 + l * 128, NN);
        }
        k_gemm<<<gemmBlocks, 256, 0, stream>>>(
            A, W2l, b2c + l * 128, g1c + l * 128, be1c + l * 128,
            sum1 + l * 128, sq1 + l * 128,
            B, sum2 + l * 128, sq2 + l * 128, NN);
    }
    k_update2<<<gemmBlocks, 256, 0, stream>>>(
        B, g2c + 3 * 128, be2c + 3 * 128, sum2 + 3 * 128, sq2 + 3 * 128,
        batch, A, gsum);
    k_pool2<<<(NG * DD + 255) / 256, 256, 0, stream>>>(gsum, goff, outw);
}

// Round 13
// 628.764 us; speedup vs baseline: 1.8249x; 1.8249x over previous
//
#include <hip/hip_runtime.h>

#define NN 50000
#define NE 500000
#define DD 128
#define NL 4
#define NG 64
#define FIXED_DIM 10000
#define BN_EPS 1e-5f
#define NB 196   // ceil(NN/256)

typedef unsigned short u16;
typedef unsigned int u32;
typedef __attribute__((ext_vector_type(8))) short bf16x8;
typedef __attribute__((ext_vector_type(4))) float f32x4;

__device__ __forceinline__ float bf2f(u16 u) {
    return __uint_as_float(((u32)u) << 16);
}
__device__ __forceinline__ u16 f2bf(float f) {
    u32 u = __float_as_uint(f);
    return (u16)((u + 0x7FFFu + ((u >> 16) & 1u)) >> 16);
}
// adaptive float-INPUT load (isbf: bf16 vs fp32)
__device__ __forceinline__ float ldf(const void* p, size_t i, int isbf) {
    return isbf ? bf2f(((const u16*)p)[i]) : ((const float*)p)[i];
}

// dtype probe on value_proj_b's first 128 u16 (256 B, in-bounds either way)
__global__ void k_detect(const void* __restrict__ vb, int* __restrict__ flag) {
    __shared__ int ok[128];
    int t = threadIdx.x;
    float v = bf2f(((const u16*)vb)[t]);
    ok[t] = (fabsf(v) < 1000.f) ? 1 : 0;   // NaN -> 0
    __syncthreads();
    for (int off = 64; off; off >>= 1) {
        if (t < off) ok[t] &= ok[t + off];
        __syncthreads();
    }
    if (t == 0) *flag = ok[0];             // 1 = bf16 inputs, 0 = fp32
}

__global__ void k_zero(float* __restrict__ p, int n) {
    int i = blockIdx.x * 256 + threadIdx.x;
    if (i < n) p[i] = 0.0f;
}
// convert 6 per-layer param tensors (each NL*DD) into one fp32 block
__global__ void k_cvt6(const void* b1, const void* b2, const void* g1,
                       const void* be1, const void* g2, const void* be2,
                       float* __restrict__ pc, const int* __restrict__ flag) {
    int t = blockIdx.x * 256 + threadIdx.x;
    if (t >= 6 * NL * DD) return;
    int p = t >> 9, j = t & 511;
    const void* s = (p == 0) ? b1 : (p == 1) ? b2 : (p == 2) ? g1
                  : (p == 3) ? be1 : (p == 4) ? g2 : be2;
    pc[t] = ldf(s, j, *flag);
}
__global__ void k_deg(const int* __restrict__ dst, int* __restrict__ deg) {
    int i = blockIdx.x * 256 + threadIdx.x;
    if (i < NE) atomicAdd(&deg[dst[i]], 1);
}
// batch is sorted: goff[g] = lower_bound(batch, g); goff[NG] = NN
__global__ void k_goff(const int* __restrict__ batch, int* __restrict__ goff) {
    int g = threadIdx.x;
    if (g > NG) return;
    int lo = 0, hi = NN;
    while (lo < hi) {
        int mid = (lo + hi) >> 1;
        if (batch[mid] < g) lo = mid + 1; else hi = mid;
    }
    goff[g] = lo;
}

// ---- parallel exclusive scan of deg -> rowptr (3 stages) ----
__global__ void k_scan1(const int* __restrict__ deg, int* __restrict__ bsum) {
    __shared__ int S[256];
    int b = blockIdx.x, t = threadIdx.x;
    int i = b * 256 + t;
    S[t] = (i < NN) ? deg[i] : 0;
    __syncthreads();
    for (int off = 128; off; off >>= 1) {
        if (t < off) S[t] += S[t + off];
        __syncthreads();
    }
    if (t == 0) bsum[b] = S[0];
}
__global__ void k_scan2(int* __restrict__ bsum) {   // 1 block, 256 thr
    __shared__ int S[256];
    int t = threadIdx.x;
    int v = (t < NB) ? bsum[t] : 0;
    S[t] = v;
    __syncthreads();
    for (int off = 1; off < 256; off <<= 1) {
        int x = (t >= off) ? S[t - off] : 0;
        __syncthreads();
        S[t] += x;
        __syncthreads();
    }
    if (t < NB) bsum[t] = S[t] - v;                 // exclusive
}
__global__ void k_scan3(const int* __restrict__ deg, const int* __restrict__ bsum,
                        int* __restrict__ rowptr) {
    __shared__ int S[256];
    int b = blockIdx.x, t = threadIdx.x;
    int i = b * 256 + t;
    int v = (i < NN) ? deg[i] : 0;
    S[t] = v;
    __syncthreads();
    for (int off = 1; off < 256; off <<= 1) {
        int x = (t >= off) ? S[t - off] : 0;
        __syncthreads();
        S[t] += x;
        __syncthreads();
    }
    if (i < NN) rowptr[i] = bsum[b] + S[t] - v;
    if (i == NN - 1) rowptr[NN] = bsum[b] + S[t];   // == NE
}

__global__ void k_fill(const int* __restrict__ src, const int* __restrict__ dst,
                       const int* __restrict__ rowptr, int* __restrict__ cursor,
                       int* __restrict__ colidx) {
    int e = blockIdx.x * 256 + threadIdx.x;
    if (e >= NE) return;
    int d = dst[e];
    int p = atomicAdd(&cursor[d], 1);
    colidx[rowptr[d] + p] = src[e];
}

// pre-swizzle 8 weight matrices into MFMA B-fragment order:
// Wsw[m*16384 + ((nt*4+ks)*64 + lane)*8 + j]
//   = W_m[ks*32 + (lane>>4)*8 + j][nt*16 + (lane&15)]   (bf16)
__global__ void k_swz(const void* __restrict__ w1, const void* __restrict__ w2,
                      u16* __restrict__ Wsw, const int* __restrict__ flag) {
    int t = blockIdx.x * 256 + threadIdx.x;   // 8*16384 = 131072
    if (t >= 8 * 16384) return;
    int m    = t >> 14;
    int idx  = t & 16383;
    int nt   = idx >> 11;
    int ks   = (idx >> 9) & 3;
    int lane = (idx >> 3) & 63;
    int j    = idx & 7;
    int row = ks * 32 + (lane >> 4) * 8 + j;
    int col = nt * 16 + (lane & 15);
    const void* src = (m < 4) ? w1 : w2;
    size_t off = (size_t)(m & 3) * DD * DD + (size_t)row * DD + col;
    Wsw[t] = f2bf(ldf(src, off, *flag));
}

// h0 = vw[feat] + vb + deg_emb[min(deg,1000)] -> B (bf16)
__global__ void k_init(const int* __restrict__ feat, const int* __restrict__ deg,
                       const void* __restrict__ vw, const void* __restrict__ vb,
                       const void* __restrict__ demb, u16* __restrict__ B,
                       const int* __restrict__ flag) {
    int t = blockIdx.x * 256 + threadIdx.x;
    if (t >= NN * DD) return;
    int n = t >> 7, c = t & 127;
    int isbf = *flag;
    int f = feat[n] % FIXED_DIM;
    int dg = min(deg[n], 1000);
    B[t] = f2bf(ldf(vw, (size_t)f * DD + c, isbf)
              + ldf(vb, c, isbf)
              + ldf(demb, (size_t)dg * DD + c, isbf));
}

// GIN aggregation with fused h-recompute, fp32 out (R10-proven numerics):
//   f(x) = AFF ? relu(a[c]*x + b[c]) : x   (a,b from prev layer's BN2 stats)
//   A[n] = f(B[n]) + sum_{j in row n} f(B[colidx[j]])
// wave = 1 row, lane = 2 cols; 4-way unrolled neighbor loop for MLP
// (sequential += keeps summation order identical to the serial loop).
template <bool AFF>
__global__ __launch_bounds__(256, 4) void k_aggr(
        const u16* __restrict__ B, const int* __restrict__ rowptr,
        const int* __restrict__ colidx,
        const float* __restrict__ gIn, const float* __restrict__ bIn,
        const float* __restrict__ sIn, const float* __restrict__ qIn,
        float* __restrict__ A) {
    int n = blockIdx.x * 4 + (threadIdx.x >> 6);
    if (n >= NN) return;
    int c = (threadIdx.x & 63) * 2;
    float a0 = 1.f, b0 = 0.f, a1 = 1.f, b1 = 0.f;
    if (AFF) {
        float inv = 1.0f / (float)NN;
        float mu0 = sIn[c] * inv, mu1 = sIn[c + 1] * inv;
        float v0 = fmaxf(qIn[c] * inv - mu0 * mu0, 0.f);
        float v1 = fmaxf(qIn[c + 1] * inv - mu1 * mu1, 0.f);
        a0 = gIn[c] * rsqrtf(v0 + BN_EPS);
        a1 = gIn[c + 1] * rsqrtf(v1 + BN_EPS);
        b0 = bIn[c] - a0 * mu0;
        b1 = bIn[c + 1] - a1 * mu1;
    }
    u32 w = *(const u32*)&B[(size_t)n * DD + c];
    float x0 = bf2f((u16)(w & 0xFFFF)), x1 = bf2f((u16)(w >> 16));
    float s0 = AFF ? fmaxf(fmaf(a0, x0, b0), 0.f) : x0;
    float s1 = AFF ? fmaxf(fmaf(a1, x1, b1), 0.f) : x1;
    int lo = rowptr[n], hi = rowptr[n + 1];
    int j = lo;
    for (; j + 4 <= hi; j += 4) {
        int m0 = colidx[j], m1 = colidx[j + 1];
        int m2 = colidx[j + 2], m3 = colidx[j + 3];
        u32 w0 = *(const u32*)&B[(size_t)m0 * DD + c];
        u32 w1v = *(const u32*)&B[(size_t)m1 * DD + c];
        u32 w2v = *(const u32*)&B[(size_t)m2 * DD + c];
        u32 w3v = *(const u32*)&B[(size_t)m3 * DD + c];
        float y;
        y = bf2f((u16)(w0 & 0xFFFF)); s0 += AFF ? fmaxf(fmaf(a0, y, b0), 0.f) : y;
        y = bf2f((u16)(w0 >> 16));    s1 += AFF ? fmaxf(fmaf(a1, y, b1), 0.f) : y;
        y = bf2f((u16)(w1v & 0xFFFF)); s0 += AFF ? fmaxf(fmaf(a0, y, b0), 0.f) : y;
        y = bf2f((u16)(w1v >> 16));    s1 += AFF ? fmaxf(fmaf(a1, y, b1), 0.f) : y;
        y = bf2f((u16)(w2v & 0xFFFF)); s0 += AFF ? fmaxf(fmaf(a0, y, b0), 0.f) : y;
        y = bf2f((u16)(w2v >> 16));    s1 += AFF ? fmaxf(fmaf(a1, y, b1), 0.f) : y;
        y = bf2f((u16)(w3v & 0xFFFF)); s0 += AFF ? fmaxf(fmaf(a0, y, b0), 0.f) : y;
        y = bf2f((u16)(w3v >> 16));    s1 += AFF ? fmaxf(fmaf(a1, y, b1), 0.f) : y;
    }
    for (; j < hi; j++) {
        int m = colidx[j];
        w = *(const u32*)&B[(size_t)m * DD + c];
        x0 = bf2f((u16)(w & 0xFFFF)); x1 = bf2f((u16)(w >> 16));
        s0 += AFF ? fmaxf(fmaf(a0, x0, b0), 0.f) : x0;
        s1 += AFF ? fmaxf(fmaf(a1, x1, b1), 0.f) : x1;
    }
    *(float2*)&A[(size_t)n * DD + c] = make_float2(s0, s1);
}

// ---- MFMA GEMM: Out = f(In) @ W + bias; f = AFF ? relu(aff*x+b) : id ----
// In fp32 (rounded to bf16 once, at staging — R10-proven numerics).
// Out fp32 (in-place A safe: block stages its own rows before writing) or bf16.
// Fused per-column sum/sumsq. LDS 50 KB -> 3 blocks/CU; Red aliases At.
template <bool OUT16, bool AFF>
__global__ __launch_bounds__(256, 3) void k_gemm(
        const float* In, const u16* __restrict__ Wsw,
        const float* __restrict__ bias,
        const float* __restrict__ gIn, const float* __restrict__ bIn,
        const float* __restrict__ sIn, const float* __restrict__ qIn,
        void* Out, float* __restrict__ ssum, float* __restrict__ ssq,
        int nRows) {
    __shared__ u16 Wl[16384];          // 32 KB swizzled W
    __shared__ u16 At[64 * 136];       // 17 KB bf16 A-tile, pitch 136
    __shared__ float affS[256];        // 1 KB
    float* RedS = (float*)At;          // alias At after MFMA loop
    float* RedQ = RedS + 512;
    const int t = threadIdx.x;
    const int row0 = blockIdx.x * 64;

    if (AFF) {
        if (t < 128) {
            float inv = 1.0f / (float)NN;
            float mu = sIn[t] * inv;
            float var = fmaxf(qIn[t] * inv - mu * mu, 0.f);
            float a = gIn[t] * rsqrtf(var + BN_EPS);
            affS[t] = a;
            affS[128 + t] = bIn[t] - a * mu;
        }
        __syncthreads();
    }

    // stage swizzled W: 2048 uint4
    {
        const uint4* s = (const uint4*)Wsw;
        uint4* d = (uint4*)Wl;
        #pragma unroll
        for (int i = 0; i < 8; i++) d[t + i * 256] = s[t + i * 256];
    }
    // stage A-tile as bf16 (+optional affine+relu in fp32 before the round)
    for (int i = t; i < 2048; i += 256) {
        int r  = i >> 5;
        int c4 = (i & 31) * 4;
        int gr = row0 + r;
        float4 v = make_float4(0.f, 0.f, 0.f, 0.f);
        if (gr < nRows) {
            v = *(const float4*)&In[(size_t)gr * DD + c4];
            if (AFF) {
                v.x = fmaxf(fmaf(affS[c4 + 0], v.x, affS[128 + c4 + 0]), 0.f);
                v.y = fmaxf(fmaf(affS[c4 + 1], v.y, affS[128 + c4 + 1]), 0.f);
                v.z = fmaxf(fmaf(affS[c4 + 2], v.z, affS[128 + c4 + 2]), 0.f);
                v.w = fmaxf(fmaf(affS[c4 + 3], v.w, affS[128 + c4 + 3]), 0.f);
            }
        }
        ushort4 o;
        o.x = f2bf(v.x); o.y = f2bf(v.y); o.z = f2bf(v.z); o.w = f2bf(v.w);
        *(ushort4*)&At[r * 136 + c4] = o;
    }
    __syncthreads();

    const int w    = t >> 6;
    const int ln   = t & 63;
    const int quad = ln >> 4;
    const int lq   = ln & 15;

    f32x4 acc[8];
    #pragma unroll
    for (int nt = 0; nt < 8; nt++) acc[nt] = (f32x4){0.f, 0.f, 0.f, 0.f};

    const u16* aRow = &At[(w * 16 + lq) * 136 + quad * 8];
    #pragma unroll
    for (int ks = 0; ks < 4; ks++) {
        bf16x8 a = *(const bf16x8*)&aRow[ks * 32];
        #pragma unroll
        for (int nt = 0; nt < 8; nt++) {
            bf16x8 b = *(const bf16x8*)&Wl[((nt * 4 + ks) * 64 + ln) * 8];
            acc[nt] = __builtin_amdgcn_mfma_f32_16x16x32_bf16(a, b, acc[nt], 0, 0, 0);
        }
    }
    __syncthreads();   // At dead; RedS/RedQ alias it

    // epilogue: D[row=quad*4+r][col=nt*16+lq]; +bias, store, fused stats
    const int rbase = row0 + w * 16 + quad * 4;
    #pragma unroll
    for (int nt = 0; nt < 8; nt++) {
        int col = nt * 16 + lq;
        float bv = bias[col];
        float s = 0.f, q = 0.f;
        #pragma unroll
        for (int r = 0; r < 4; r++) {
            int grow = rbase + r;
            if (grow < nRows) {
                float val = acc[nt][r] + bv;
                size_t o = (size_t)grow * DD + col;
                if (OUT16) ((u16*)Out)[o] = f2bf(val);
                else       ((float*)Out)[o] = val;
                s += val; q += val * val;
            }
        }
        s += __shfl_xor(s, 16); q += __shfl_xor(q, 16);
        s += __shfl_xor(s, 32); q += __shfl_xor(q, 32);
        if (quad == 0) { RedS[w * 128 + col] = s; RedQ[w * 128 + col] = q; }
    }
    __syncthreads();
    if (t < 128) {
        float s = RedS[t] + RedS[128 + t] + RedS[256 + t] + RedS[384 + t];
        float q = RedQ[t] + RedQ[128 + t] + RedQ[256 + t] + RedQ[384 + t];
        atomicAdd(&ssum[t], s);
        atomicAdd(&ssq[t], q);
    }
}

// final h = relu(a*z2+b) -> A (fp32) + segment-accumulated pool partials.
__global__ __launch_bounds__(256, 4) void k_update2(
        const u16* __restrict__ Bz,
        const float* __restrict__ gIn, const float* __restrict__ bIn,
        const float* __restrict__ sIn, const float* __restrict__ qIn,
        const int* __restrict__ batch, float* __restrict__ A,
        float* __restrict__ gsum) {
    const int t = threadIdx.x;
    const int c = t & 127;
    const int half = t >> 7;           // rows half + 2i
    const int r0 = blockIdx.x * 64;
    float inv = 1.0f / (float)NN;
    float mu = sIn[c] * inv;
    float var = fmaxf(qIn[c] * inv - mu * mu, 0.f);
    float a = gIn[c] * rsqrtf(var + BN_EPS);
    float bb = bIn[c] - a * mu;
    float acc = 0.f;
    int curg = -1;
    for (int i = 0; i < 32; i++) {
        int r = r0 + half + 2 * i;
        if (r >= NN) break;
        int gg = batch[r];
        if (gg != curg) {
            if (curg >= 0) atomicAdd(&gsum[(size_t)curg * DD + c], acc);
            acc = 0.f; curg = gg;
        }
        float v = fmaxf(fmaf(a, bf2f(Bz[(size_t)r * DD + c]), bb), 0.f);
        A[(size_t)r * DD + c] = v;
        acc += v;
    }
    if (curg >= 0) atomicAdd(&gsum[(size_t)curg * DD + c], acc);
}

__global__ void k_pool2(const float* __restrict__ gsum, const int* __restrict__ goff,
                        float* __restrict__ out) {
    int t = blockIdx.x * 256 + threadIdx.x;   // G*DD exact
    int g = t >> 7;
    float cnt = fmaxf((float)(goff[g + 1] - goff[g]), 1.0f);
    out[t] = gsum[t] / cnt;
}

extern "C" void kernel_launch(void* const* d_in, const int* in_sizes, int n_in,
                              void* d_out, int out_size, void* d_ws, size_t ws_size,
                              hipStream_t stream) {
    const int* feat  = (const int*)d_in[0];
    const int* ei    = (const int*)d_in[1];
    const int* batch = (const int*)d_in[2];
    const void* vw   = d_in[3];
    const void* vb   = d_in[4];
    const void* demb = d_in[5];
    const void* w1   = d_in[6];
    const void* b1   = d_in[7];
    const void* g1   = d_in[8];
    const void* be1  = d_in[9];
    const void* w2   = d_in[10];
    const void* b2   = d_in[11];
    const void* g2   = d_in[12];
    const void* be2  = d_in[13];

    const int* src = ei;
    const int* dst = ei + NE;
    const size_t ND = (size_t)NN * DD;

    // ---- workspace layout (~15.6 MB; R5..R12 prove ws >= this) ----
    float* pc     = (float*)d_ws;            // 3072: b1,b2,g1,be1,g2,be2
    int*   flag   = (int*)(pc + 3072);       // 64
    float* stats  = (float*)(flag + 64);     // 2048 [zero from here...]
    float* gsum   = stats + 2048;            // 8192
    int*   deg    = (int*)(gsum + 8192);     // NN
    int*   cursor = deg + NN;                // NN   [...to here]
    int*   bsum   = cursor + NN;             // 256
    int*   goff   = bsum + 256;              // 128 (65 used)
    int*   rowptr = goff + 128;              // NN+64
    int*   colidx = rowptr + NN + 64;        // NE
    u16*   Wsw    = (u16*)(colidx + NE);     // 8*16384 u16
    u16*   B      = Wsw + 8 * 16384;         // ND bf16

    float* b1c  = pc;
    float* b2c  = pc + 512;
    float* g1c  = pc + 1024;
    float* be1c = pc + 1536;
    float* g2c  = pc + 2048;
    float* be2c = pc + 2560;
    float* sum1 = stats;          // [NL][128]
    float* sq1  = stats + 512;
    float* sum2 = stats + 1024;
    float* sq2  = stats + 1536;

    float* outw = (float*)d_out;             // [0, NG*DD): graph_feature
    float* A    = outw + (size_t)NG * DD;    // h region: fp32 Agg/z1 scratch, final h

    const int zwords = 2048 + 8192 + NN + NN;   // stats, gsum, deg, cursor
    const int gridND = (int)((ND + 255) / 256);
    const int gemmBlocks = (NN + 63) / 64;   // 782
    const int aggrBlocks = (NN + 3) / 4;     // 12500

    k_detect<<<1, 128, 0, stream>>>(vb, flag);
    k_zero<<<(zwords + 255) / 256, 256, 0, stream>>>(stats, zwords);
    k_cvt6<<<(6 * NL * DD + 255) / 256, 256, 0, stream>>>(b1, b2, g1, be1, g2, be2, pc, flag);
    k_swz<<<(8 * 16384) / 256, 256, 0, stream>>>(w1, w2, Wsw, flag);
    k_deg<<<(NE + 255) / 256, 256, 0, stream>>>(dst, deg);
    k_goff<<<1, 128, 0, stream>>>(batch, goff);
    k_scan1<<<NB, 256, 0, stream>>>(deg, bsum);
    k_scan2<<<1, 256, 0, stream>>>(bsum);
    k_scan3<<<NB, 256, 0, stream>>>(deg, bsum, rowptr);
    k_fill<<<(NE + 255) / 256, 256, 0, stream>>>(src, dst, rowptr, cursor, colidx);
    k_init<<<gridND, 256, 0, stream>>>(feat, deg, vw, vb, demb, B, flag);

    for (int l = 0; l < NL; l++) {
        const u16* W1l = Wsw + (size_t)l * 16384;
        const u16* W2l = Wsw + (size_t)(4 + l) * 16384;
        if (l == 0) {
            k_aggr<false><<<aggrBlocks, 256, 0, stream>>>(
                B, rowptr, colidx, nullptr, nullptr, nullptr, nullptr, A);
        } else {
            k_aggr<true><<<aggrBlocks, 256, 0, stream>>>(
                B, rowptr, colidx, g2c + (l - 1) * 128, be2c + (l - 1) * 128,
                sum2 + (l - 1) * 128, sq2 + (l - 1) * 128, A);
        }
        // GEMM1: A (fp32 agg) -> A (fp32 z1, in-place)
        k_gemm<false, false><<<gemmBlocks, 256, 0, stream>>>(
            A, W1l, b1c + l * 128, nullptr, nullptr, nullptr, nullptr,
            A, sum1 + l * 128, sq1 + l * 128, NN);
        // GEMM2: A (fp32 z1) -> B (bf16 z2), affine from BN1 stats
        k_gemm<true, true><<<gemmBlocks, 256, 0, stream>>>(
            A, W2l, b2c + l * 128, g1c + l * 128, be1c + l * 128,
            sum1 + l * 128, sq1 + l * 128,
            B, sum2 + l * 128, sq2 + l * 128, NN);
    }
    k_update2<<<gemmBlocks, 256, 0, stream>>>(
        B, g2c + 3 * 128, be2c + 3 * 128, sum2 + 3 * 128, sq2 + 3 * 128,
        batch, A, gsum);
    k_pool2<<<(NG * DD + 255) / 256, 256, 0, stream>>>(gsum, goff, outw);
}

// Round 14
// 617.294 us; speedup vs baseline: 1.8588x; 1.0186x over previous
//
#include <hip/hip_runtime.h>

#define NN 50000
#define NE 500000
#define DD 128
#define NL 4
#define NG 64
#define FIXED_DIM 10000
#define BN_EPS 1e-5f
#define NB 196   // ceil(NN/256)

typedef unsigned short u16;
typedef unsigned int u32;
typedef __attribute__((ext_vector_type(8))) short bf16x8;
typedef __attribute__((ext_vector_type(4))) float f32x4;

__device__ __forceinline__ float bf2f(u16 u) {
    return __uint_as_float(((u32)u) << 16);
}
__device__ __forceinline__ u16 f2bf(float f) {
    u32 u = __float_as_uint(f);
    return (u16)((u + 0x7FFFu + ((u >> 16) & 1u)) >> 16);
}
// adaptive float-INPUT load (isbf: bf16 vs fp32)
__device__ __forceinline__ float ldf(const void* p, size_t i, int isbf) {
    return isbf ? bf2f(((const u16*)p)[i]) : ((const float*)p)[i];
}

// dtype probe on value_proj_b's first 128 u16 (256 B, in-bounds either way)
__global__ void k_detect(const void* __restrict__ vb, int* __restrict__ flag) {
    __shared__ int ok[128];
    int t = threadIdx.x;
    float v = bf2f(((const u16*)vb)[t]);
    ok[t] = (fabsf(v) < 1000.f) ? 1 : 0;   // NaN -> 0
    __syncthreads();
    for (int off = 64; off; off >>= 1) {
        if (t < off) ok[t] &= ok[t + off];
        __syncthreads();
    }
    if (t == 0) *flag = ok[0];             // 1 = bf16 inputs, 0 = fp32
}

__global__ void k_zero(float* __restrict__ p, int n) {
    int i = blockIdx.x * 256 + threadIdx.x;
    if (i < n) p[i] = 0.0f;
}
// convert 6 per-layer param tensors (each NL*DD) into one fp32 block
__global__ void k_cvt6(const void* b1, const void* b2, const void* g1,
                       const void* be1, const void* g2, const void* be2,
                       float* __restrict__ pc, const int* __restrict__ flag) {
    int t = blockIdx.x * 256 + threadIdx.x;
    if (t >= 6 * NL * DD) return;
    int p = t >> 9, j = t & 511;
    const void* s = (p == 0) ? b1 : (p == 1) ? b2 : (p == 2) ? g1
                  : (p == 3) ? be1 : (p == 4) ? g2 : be2;
    pc[t] = ldf(s, j, *flag);
}
__global__ void k_deg(const int* __restrict__ dst, int* __restrict__ deg) {
    int i = blockIdx.x * 256 + threadIdx.x;
    if (i < NE) atomicAdd(&deg[dst[i]], 1);
}
// batch is sorted: goff[g] = lower_bound(batch, g); goff[NG] = NN
__global__ void k_goff(const int* __restrict__ batch, int* __restrict__ goff) {
    int g = threadIdx.x;
    if (g > NG) return;
    int lo = 0, hi = NN;
    while (lo < hi) {
        int mid = (lo + hi) >> 1;
        if (batch[mid] < g) lo = mid + 1; else hi = mid;
    }
    goff[g] = lo;
}

// ---- parallel exclusive scan of deg -> rowptr (3 stages) ----
__global__ void k_scan1(const int* __restrict__ deg, int* __restrict__ bsum) {
    __shared__ int S[256];
    int b = blockIdx.x, t = threadIdx.x;
    int i = b * 256 + t;
    S[t] = (i < NN) ? deg[i] : 0;
    __syncthreads();
    for (int off = 128; off; off >>= 1) {
        if (t < off) S[t] += S[t + off];
        __syncthreads();
    }
    if (t == 0) bsum[b] = S[0];
}
__global__ void k_scan2(int* __restrict__ bsum) {   // 1 block, 256 thr
    __shared__ int S[256];
    int t = threadIdx.x;
    int v = (t < NB) ? bsum[t] : 0;
    S[t] = v;
    __syncthreads();
    for (int off = 1; off < 256; off <<= 1) {
        int x = (t >= off) ? S[t - off] : 0;
        __syncthreads();
        S[t] += x;
        __syncthreads();
    }
    if (t < NB) bsum[t] = S[t] - v;                 // exclusive
}
__global__ void k_scan3(const int* __restrict__ deg, const int* __restrict__ bsum,
                        int* __restrict__ rowptr) {
    __shared__ int S[256];
    int b = blockIdx.x, t = threadIdx.x;
    int i = b * 256 + t;
    int v = (i < NN) ? deg[i] : 0;
    S[t] = v;
    __syncthreads();
    for (int off = 1; off < 256; off <<= 1) {
        int x = (t >= off) ? S[t - off] : 0;
        __syncthreads();
        S[t] += x;
        __syncthreads();
    }
    if (i < NN) rowptr[i] = bsum[b] + S[t] - v;
    if (i == NN - 1) rowptr[NN] = bsum[b] + S[t];   // == NE
}

__global__ void k_fill(const int* __restrict__ src, const int* __restrict__ dst,
                       const int* __restrict__ rowptr, int* __restrict__ cursor,
                       int* __restrict__ colidx) {
    int e = blockIdx.x * 256 + threadIdx.x;
    if (e >= NE) return;
    int d = dst[e];
    int p = atomicAdd(&cursor[d], 1);
    colidx[rowptr[d] + p] = src[e];
}

// pre-swizzle 8 weight matrices into MFMA B-fragment order:
// Wsw[m*16384 + ((nt*4+ks)*64 + lane)*8 + j]
//   = W_m[ks*32 + (lane>>4)*8 + j][nt*16 + (lane&15)]   (bf16)
__global__ void k_swz(const void* __restrict__ w1, const void* __restrict__ w2,
                      u16* __restrict__ Wsw, const int* __restrict__ flag) {
    int t = blockIdx.x * 256 + threadIdx.x;   // 8*16384 = 131072
    if (t >= 8 * 16384) return;
    int m    = t >> 14;
    int idx  = t & 16383;
    int nt   = idx >> 11;
    int ks   = (idx >> 9) & 3;
    int lane = (idx >> 3) & 63;
    int j    = idx & 7;
    int row = ks * 32 + (lane >> 4) * 8 + j;
    int col = nt * 16 + (lane & 15);
    const void* src = (m < 4) ? w1 : w2;
    size_t off = (size_t)(m & 3) * DD * DD + (size_t)row * DD + col;
    Wsw[t] = f2bf(ldf(src, off, *flag));
}

// h0 = vw[feat] + vb + deg_emb[min(deg,1000)] -> B (bf16)
__global__ void k_init(const int* __restrict__ feat, const int* __restrict__ deg,
                       const void* __restrict__ vw, const void* __restrict__ vb,
                       const void* __restrict__ demb, u16* __restrict__ B,
                       const int* __restrict__ flag) {
    int t = blockIdx.x * 256 + threadIdx.x;
    if (t >= NN * DD) return;
    int n = t >> 7, c = t & 127;
    int isbf = *flag;
    int f = feat[n] % FIXED_DIM;
    int dg = min(deg[n], 1000);
    B[t] = f2bf(ldf(vw, (size_t)f * DD + c, isbf)
              + ldf(vb, c, isbf)
              + ldf(demb, (size_t)dg * DD + c, isbf));
}

// GIN aggregation with fused h-recompute:
//   f(x) = AFF ? relu(a[c]*x + b[c]) : x   (a,b from prev layer's BN2 stats)
//   Agg[n] = f(B[n]) + sum_{j in row n} f(B[colidx[j]])
// O16: bf16 out (bit-identical to fp32-out + bf16 round at GEMM staging).
// wave = 1 row, lane = 2 cols; 4-way unrolled neighbor loop (order preserved).
// (256,8): 8 blocks/CU, 32 waves — gather is latency-bound, max TLP.
template <bool AFF, bool O16>
__global__ __launch_bounds__(256, 8) void k_aggr(
        const u16* __restrict__ B, const int* __restrict__ rowptr,
        const int* __restrict__ colidx,
        const float* __restrict__ gIn, const float* __restrict__ bIn,
        const float* __restrict__ sIn, const float* __restrict__ qIn,
        void* __restrict__ Agg) {
    int n = blockIdx.x * 4 + (threadIdx.x >> 6);
    if (n >= NN) return;
    int c = (threadIdx.x & 63) * 2;
    float a0 = 1.f, b0 = 0.f, a1 = 1.f, b1 = 0.f;
    if (AFF) {
        float inv = 1.0f / (float)NN;
        float mu0 = sIn[c] * inv, mu1 = sIn[c + 1] * inv;
        float v0 = fmaxf(qIn[c] * inv - mu0 * mu0, 0.f);
        float v1 = fmaxf(qIn[c + 1] * inv - mu1 * mu1, 0.f);
        a0 = gIn[c] * rsqrtf(v0 + BN_EPS);
        a1 = gIn[c + 1] * rsqrtf(v1 + BN_EPS);
        b0 = bIn[c] - a0 * mu0;
        b1 = bIn[c + 1] - a1 * mu1;
    }
    u32 w = *(const u32*)&B[(size_t)n * DD + c];
    float x0 = bf2f((u16)(w & 0xFFFF)), x1 = bf2f((u16)(w >> 16));
    float s0 = AFF ? fmaxf(fmaf(a0, x0, b0), 0.f) : x0;
    float s1 = AFF ? fmaxf(fmaf(a1, x1, b1), 0.f) : x1;
    int lo = rowptr[n], hi = rowptr[n + 1];
    int j = lo;
    for (; j + 4 <= hi; j += 4) {
        int m0 = colidx[j], m1 = colidx[j + 1];
        int m2 = colidx[j + 2], m3 = colidx[j + 3];
        u32 w0 = *(const u32*)&B[(size_t)m0 * DD + c];
        u32 w1v = *(const u32*)&B[(size_t)m1 * DD + c];
        u32 w2v = *(const u32*)&B[(size_t)m2 * DD + c];
        u32 w3v = *(const u32*)&B[(size_t)m3 * DD + c];
        float y;
        y = bf2f((u16)(w0 & 0xFFFF)); s0 += AFF ? fmaxf(fmaf(a0, y, b0), 0.f) : y;
        y = bf2f((u16)(w0 >> 16));    s1 += AFF ? fmaxf(fmaf(a1, y, b1), 0.f) : y;
        y = bf2f((u16)(w1v & 0xFFFF)); s0 += AFF ? fmaxf(fmaf(a0, y, b0), 0.f) : y;
        y = bf2f((u16)(w1v >> 16));    s1 += AFF ? fmaxf(fmaf(a1, y, b1), 0.f) : y;
        y = bf2f((u16)(w2v & 0xFFFF)); s0 += AFF ? fmaxf(fmaf(a0, y, b0), 0.f) : y;
        y = bf2f((u16)(w2v >> 16));    s1 += AFF ? fmaxf(fmaf(a1, y, b1), 0.f) : y;
        y = bf2f((u16)(w3v & 0xFFFF)); s0 += AFF ? fmaxf(fmaf(a0, y, b0), 0.f) : y;
        y = bf2f((u16)(w3v >> 16));    s1 += AFF ? fmaxf(fmaf(a1, y, b1), 0.f) : y;
    }
    for (; j < hi; j++) {
        int m = colidx[j];
        w = *(const u32*)&B[(size_t)m * DD + c];
        x0 = bf2f((u16)(w & 0xFFFF)); x1 = bf2f((u16)(w >> 16));
        s0 += AFF ? fmaxf(fmaf(a0, x0, b0), 0.f) : x0;
        s1 += AFF ? fmaxf(fmaf(a1, x1, b1), 0.f) : x1;
    }
    if (O16) {
        *(u32*)&((u16*)Agg)[(size_t)n * DD + c] =
            ((u32)f2bf(s1) << 16) | (u32)f2bf(s0);
    } else {
        *(float2*)&((float*)Agg)[(size_t)n * DD + c] = make_float2(s0, s1);
    }
}

// ---- MFMA GEMM: Out = f(In) @ W + bias; f = AFF ? relu(aff*x+b) : id ----
// IN16: In is bf16 (pure copy staging). Else fp32, rounded once at staging.
// Out fp32 (in-place safe) or bf16. Fused per-column sum/sumsq.
// LDS 50 KB -> 3 blocks/CU; Red buffers alias At (dead after MFMA loop).
template <bool IN16, bool OUT16, bool AFF>
__global__ __launch_bounds__(256, 3) void k_gemm(
        const void* In, const u16* __restrict__ Wsw,
        const float* __restrict__ bias,
        const float* __restrict__ gIn, const float* __restrict__ bIn,
        const float* __restrict__ sIn, const float* __restrict__ qIn,
        void* Out, float* __restrict__ ssum, float* __restrict__ ssq,
        int nRows) {
    __shared__ u16 Wl[16384];          // 32 KB swizzled W
    __shared__ u16 At[64 * 136];       // 17 KB bf16 A-tile, pitch 136
    __shared__ float affS[256];        // 1 KB
    float* RedS = (float*)At;          // alias At after MFMA loop
    float* RedQ = RedS + 512;
    const int t = threadIdx.x;
    const int row0 = blockIdx.x * 64;

    if (AFF) {
        if (t < 128) {
            float inv = 1.0f / (float)NN;
            float mu = sIn[t] * inv;
            float var = fmaxf(qIn[t] * inv - mu * mu, 0.f);
            float a = gIn[t] * rsqrtf(var + BN_EPS);
            affS[t] = a;
            affS[128 + t] = bIn[t] - a * mu;
        }
        __syncthreads();
    }

    // stage swizzled W: 2048 uint4
    {
        const uint4* s = (const uint4*)Wsw;
        uint4* d = (uint4*)Wl;
        #pragma unroll
        for (int i = 0; i < 8; i++) d[t + i * 256] = s[t + i * 256];
    }
    // stage A-tile
    if (IN16) {
        // bf16 -> bf16 pure copy (AFF not supported on this path)
        for (int i = t; i < 1024; i += 256) {
            int r  = i >> 4;
            int c8 = (i & 15) * 8;
            int gr = row0 + r;
            uint4 v = make_uint4(0u, 0u, 0u, 0u);
            if (gr < nRows) v = *(const uint4*)&((const u16*)In)[(size_t)gr * DD + c8];
            *(uint4*)&At[r * 136 + c8] = v;
        }
    } else {
        for (int i = t; i < 2048; i += 256) {
            int r  = i >> 5;
            int c4 = (i & 31) * 4;
            int gr = row0 + r;
            float4 v = make_float4(0.f, 0.f, 0.f, 0.f);
            if (gr < nRows) {
                v = *(const float4*)&((const float*)In)[(size_t)gr * DD + c4];
                if (AFF) {
                    v.x = fmaxf(fmaf(affS[c4 + 0], v.x, affS[128 + c4 + 0]), 0.f);
                    v.y = fmaxf(fmaf(affS[c4 + 1], v.y, affS[128 + c4 + 1]), 0.f);
                    v.z = fmaxf(fmaf(affS[c4 + 2], v.z, affS[128 + c4 + 2]), 0.f);
                    v.w = fmaxf(fmaf(affS[c4 + 3], v.w, affS[128 + c4 + 3]), 0.f);
                }
            }
            ushort4 o;
            o.x = f2bf(v.x); o.y = f2bf(v.y); o.z = f2bf(v.z); o.w = f2bf(v.w);
            *(ushort4*)&At[r * 136 + c4] = o;
        }
    }
    __syncthreads();

    const int w    = t >> 6;
    const int ln   = t & 63;
    const int quad = ln >> 4;
    const int lq   = ln & 15;

    f32x4 acc[8];
    #pragma unroll
    for (int nt = 0; nt < 8; nt++) acc[nt] = (f32x4){0.f, 0.f, 0.f, 0.f};

    const u16* aRow = &At[(w * 16 + lq) * 136 + quad * 8];
    #pragma unroll
    for (int ks = 0; ks < 4; ks++) {
        bf16x8 a = *(const bf16x8*)&aRow[ks * 32];
        #pragma unroll
        for (int nt = 0; nt < 8; nt++) {
            bf16x8 b = *(const bf16x8*)&Wl[((nt * 4 + ks) * 64 + ln) * 8];
            acc[nt] = __builtin_amdgcn_mfma_f32_16x16x32_bf16(a, b, acc[nt], 0, 0, 0);
        }
    }
    __syncthreads();   // At dead; RedS/RedQ alias it

    // epilogue: D[row=quad*4+r][col=nt*16+lq]; +bias, store, fused stats
    const int rbase = row0 + w * 16 + quad * 4;
    #pragma unroll
    for (int nt = 0; nt < 8; nt++) {
        int col = nt * 16 + lq;
        float bv = bias[col];
        float s = 0.f, q = 0.f;
        #pragma unroll
        for (int r = 0; r < 4; r++) {
            int grow = rbase + r;
            if (grow < nRows) {
                float val = acc[nt][r] + bv;
                size_t o = (size_t)grow * DD + col;
                if (OUT16) ((u16*)Out)[o] = f2bf(val);
                else       ((float*)Out)[o] = val;
                s += val; q += val * val;
            }
        }
        s += __shfl_xor(s, 16); q += __shfl_xor(q, 16);
        s += __shfl_xor(s, 32); q += __shfl_xor(q, 32);
        if (quad == 0) { RedS[w * 128 + col] = s; RedQ[w * 128 + col] = q; }
    }
    __syncthreads();
    if (t < 128) {
        float s = RedS[t] + RedS[128 + t] + RedS[256 + t] + RedS[384 + t];
        float q = RedQ[t] + RedQ[128 + t] + RedQ[256 + t] + RedQ[384 + t];
        atomicAdd(&ssum[t], s);
        atomicAdd(&ssq[t], q);
    }
}

// final h = relu(a*z2+b) -> A (fp32) + segment-accumulated pool partials.
__global__ __launch_bounds__(256, 4) void k_update2(
        const u16* __restrict__ Bz,
        const float* __restrict__ gIn, const float* __restrict__ bIn,
        const float* __restrict__ sIn, const float* __restrict__ qIn,
        const int* __restrict__ batch, float* __restrict__ A,
        float* __restrict__ gsum) {
    const int t = threadIdx.x;
    const int c = t & 127;
    const int half = t >> 7;           // rows half + 2i
    const int r0 = blockIdx.x * 64;
    float inv = 1.0f / (float)NN;
    float mu = sIn[c] * inv;
    float var = fmaxf(qIn[c] * inv - mu * mu, 0.f);
    float a = gIn[c] * rsqrtf(var + BN_EPS);
    float bb = bIn[c] - a * mu;
    float acc = 0.f;
    int curg = -1;
    for (int i = 0; i < 32; i++) {
        int r = r0 + half + 2 * i;
        if (r >= NN) break;
        int gg = batch[r];
        if (gg != curg) {
            if (curg >= 0) atomicAdd(&gsum[(size_t)curg * DD + c], acc);
            acc = 0.f; curg = gg;
        }
        float v = fmaxf(fmaf(a, bf2f(Bz[(size_t)r * DD + c]), bb), 0.f);
        A[(size_t)r * DD + c] = v;
        acc += v;
    }
    if (curg >= 0) atomicAdd(&gsum[(size_t)curg * DD + c], acc);
}

__global__ void k_pool2(const float* __restrict__ gsum, const int* __restrict__ goff,
                        float* __restrict__ out) {
    int t = blockIdx.x * 256 + threadIdx.x;   // G*DD exact
    int g = t >> 7;
    float cnt = fmaxf((float)(goff[g + 1] - goff[g]), 1.0f);
    out[t] = gsum[t] / cnt;
}

extern "C" void kernel_launch(void* const* d_in, const int* in_sizes, int n_in,
                              void* d_out, int out_size, void* d_ws, size_t ws_size,
                              hipStream_t stream) {
    const int* feat  = (const int*)d_in[0];
    const int* ei    = (const int*)d_in[1];
    const int* batch = (const int*)d_in[2];
    const void* vw   = d_in[3];
    const void* vb   = d_in[4];
    const void* demb = d_in[5];
    const void* w1   = d_in[6];
    const void* b1   = d_in[7];
    const void* g1   = d_in[8];
    const void* be1  = d_in[9];
    const void* w2   = d_in[10];
    const void* b2   = d_in[11];
    const void* g2   = d_in[12];
    const void* be2  = d_in[13];

    const int* src = ei;
    const int* dst = ei + NE;
    const size_t ND = (size_t)NN * DD;

    // ---- workspace layout (~28.4 MB with bf16 Agg; fill profile shows ws≈256 MB) ----
    float* pc     = (float*)d_ws;            // 3072: b1,b2,g1,be1,g2,be2
    int*   flag   = (int*)(pc + 3072);       // 64
    float* stats  = (float*)(flag + 64);     // 2048 [zero from here...]
    float* gsum   = stats + 2048;            // 8192
    int*   deg    = (int*)(gsum + 8192);     // NN
    int*   cursor = deg + NN;                // NN   [...to here]
    int*   bsum   = cursor + NN;             // 256
    int*   goff   = bsum + 256;              // 128 (65 used)
    int*   rowptr = goff + 128;              // NN+64
    int*   colidx = rowptr + NN + 64;        // NE
    u16*   Wsw    = (u16*)(colidx + NE);     // 8*16384 u16
    u16*   B      = Wsw + 8 * 16384;         // ND bf16
    u16*   Agg16  = B + ND;                  // ND bf16 (fast path)

    size_t needFast = (size_t)((char*)(Agg16 + ND) - (char*)d_ws);
    const bool fastAgg = (ws_size >= needFast);

    float* b1c  = pc;
    float* b2c  = pc + 512;
    float* g1c  = pc + 1024;
    float* be1c = pc + 1536;
    float* g2c  = pc + 2048;
    float* be2c = pc + 2560;
    float* sum1 = stats;          // [NL][128]
    float* sq1  = stats + 512;
    float* sum2 = stats + 1024;
    float* sq2  = stats + 1536;

    float* outw = (float*)d_out;             // [0, NG*DD): graph_feature
    float* A    = outw + (size_t)NG * DD;    // h region: fp32 z1 scratch, final h

    const int zwords = 2048 + 8192 + NN + NN;   // stats, gsum, deg, cursor
    const int gridND = (int)((ND + 255) / 256);
    const int gemmBlocks = (NN + 63) / 64;   // 782
    const int aggrBlocks = (NN + 3) / 4;     // 12500

    k_detect<<<1, 128, 0, stream>>>(vb, flag);
    k_zero<<<(zwords + 255) / 256, 256, 0, stream>>>(stats, zwords);
    k_cvt6<<<(6 * NL * DD + 255) / 256, 256, 0, stream>>>(b1, b2, g1, be1, g2, be2, pc, flag);
    k_swz<<<(8 * 16384) / 256, 256, 0, stream>>>(w1, w2, Wsw, flag);
    k_deg<<<(NE + 255) / 256, 256, 0, stream>>>(dst, deg);
    k_goff<<<1, 128, 0, stream>>>(batch, goff);
    k_scan1<<<NB, 256, 0, stream>>>(deg, bsum);
    k_scan2<<<1, 256, 0, stream>>>(bsum);
    k_scan3<<<NB, 256, 0, stream>>>(deg, bsum, rowptr);
    k_fill<<<(NE + 255) / 256, 256, 0, stream>>>(src, dst, rowptr, cursor, colidx);
    k_init<<<gridND, 256, 0, stream>>>(feat, deg, vw, vb, demb, B, flag);

    for (int l = 0; l < NL; l++) {
        const u16* W1l = Wsw + (size_t)l * 16384;
        const u16* W2l = Wsw + (size_t)(4 + l) * 16384;
        const float* pg = g2c + (l - 1) * 128;
        const float* pb = be2c + (l - 1) * 128;
        const float* ps = sum2 + (l - 1) * 128;
        const float* pq = sq2 + (l - 1) * 128;

        if (fastAgg) {
            if (l == 0)
                k_aggr<false, true><<<aggrBlocks, 256, 0, stream>>>(
                    B, rowptr, colidx, nullptr, nullptr, nullptr, nullptr, Agg16);
            else
                k_aggr<true, true><<<aggrBlocks, 256, 0, stream>>>(
                    B, rowptr, colidx, pg, pb, ps, pq, Agg16);
            // GEMM1: Agg16 (bf16) -> A (fp32 z1)
            k_gemm<true, false, false><<<gemmBlocks, 256, 0, stream>>>(
                Agg16, W1l, b1c + l * 128, nullptr, nullptr, nullptr, nullptr,
                A, sum1 + l * 128, sq1 + l * 128, NN);
        } else {
            if (l == 0)
                k_aggr<false, false><<<aggrBlocks, 256, 0, stream>>>(
                    B, rowptr, colidx, nullptr, nullptr, nullptr, nullptr, A);
            else
                k_aggr<true, false><<<aggrBlocks, 256, 0, stream>>>(
                    B, rowptr, colidx, pg, pb, ps, pq, A);
            // GEMM1: A (fp32 agg) -> A (fp32 z1, in-place)
            k_gemm<false, false, false><<<gemmBlocks, 256, 0, stream>>>(
                A, W1l, b1c + l * 128, nullptr, nullptr, nullptr, nullptr,
                A, sum1 + l * 128, sq1 + l * 128, NN);
        }
        // GEMM2: A (fp32 z1) -> B (bf16 z2), affine from BN1 stats
        k_gemm<false, true, true><<<gemmBlocks, 256, 0, stream>>>(
            A, W2l, b2c + l * 128, g1c + l * 128, be1c + l * 128,
            sum1 + l * 128, sq1 + l * 128,
            B, sum2 + l * 128, sq2 + l * 128, NN);
    }
    k_update2<<<gemmBlocks, 256, 0, stream>>>(
        B, g2c + 3 * 128, be2c + 3 * 128, sum2 + 3 * 128, sq2 + 3 * 128,
        batch, A, gsum);
    k_pool2<<<(NG * DD + 255) / 256, 256, 0, stream>>>(gsum, goff, outw);
}

// Round 15
// 529.044 us; speedup vs baseline: 2.1689x; 1.1668x over previous
//
#include <hip/hip_runtime.h>

#define NN 50000
#define NE 500000
#define DD 128
#define NL 4
#define NG 64
#define FIXED_DIM 10000
#define BN_EPS 1e-5f
#define NB 196   // ceil(NN/256)

typedef unsigned short u16;
typedef unsigned int u32;
typedef __attribute__((ext_vector_type(8))) short bf16x8;
typedef __attribute__((ext_vector_type(4))) float f32x4;

__device__ __forceinline__ float bf2f(u16 u) {
    return __uint_as_float(((u32)u) << 16);
}
__device__ __forceinline__ u16 f2bf(float f) {
    u32 u = __float_as_uint(f);
    return (u16)((u + 0x7FFFu + ((u >> 16) & 1u)) >> 16);
}
// adaptive float-INPUT load (isbf: bf16 vs fp32)
__device__ __forceinline__ float ldf(const void* p, size_t i, int isbf) {
    return isbf ? bf2f(((const u16*)p)[i]) : ((const float*)p)[i];
}

// fused preamble: block 0 = dtype probe; block 1 = goff binary search;
// blocks 2+ = zero of [stats .. cursor] region (no cross-block deps).
__global__ void k_pre(const void* __restrict__ vb, int* __restrict__ flag,
                      const int* __restrict__ batch, int* __restrict__ goff,
                      float* __restrict__ zbase, int zwords) {
    int b = blockIdx.x, t = threadIdx.x;
    if (b == 0) {
        __shared__ int ok[256];
        float v = (t < 128) ? bf2f(((const u16*)vb)[t]) : 0.f;
        ok[t] = (t < 128) ? ((fabsf(v) < 1000.f) ? 1 : 0) : 1;
        __syncthreads();
        for (int off = 128; off; off >>= 1) {
            if (t < off) ok[t] &= ok[t + off];
            __syncthreads();
        }
        if (t == 0) *flag = ok[0];
    } else if (b == 1) {
        if (t <= NG) {
            int lo = 0, hi = NN;
            while (lo < hi) {
                int mid = (lo + hi) >> 1;
                if (batch[mid] < t) lo = mid + 1; else hi = mid;
            }
            goff[t] = lo;
        }
    } else {
        int i = (b - 2) * 256 + t;
        if (i < zwords) zbase[i] = 0.f;
    }
}

// convert 6 per-layer param tensors (each NL*DD) into one fp32 block
__global__ void k_cvt6(const void* b1, const void* b2, const void* g1,
                       const void* be1, const void* g2, const void* be2,
                       float* __restrict__ pc, const int* __restrict__ flag) {
    int t = blockIdx.x * 256 + threadIdx.x;
    if (t >= 6 * NL * DD) return;
    int p = t >> 9, j = t & 511;
    const void* s = (p == 0) ? b1 : (p == 1) ? b2 : (p == 2) ? g1
                  : (p == 3) ? be1 : (p == 4) ? g2 : be2;
    pc[t] = ldf(s, j, *flag);
}
__global__ void k_deg(const int* __restrict__ dst, int* __restrict__ deg) {
    int i = blockIdx.x * 256 + threadIdx.x;
    if (i < NE) atomicAdd(&deg[dst[i]], 1);
}

// ---- parallel exclusive scan of deg -> rowptr (3 stages) ----
__global__ void k_scan1(const int* __restrict__ deg, int* __restrict__ bsum) {
    __shared__ int S[256];
    int b = blockIdx.x, t = threadIdx.x;
    int i = b * 256 + t;
    S[t] = (i < NN) ? deg[i] : 0;
    __syncthreads();
    for (int off = 128; off; off >>= 1) {
        if (t < off) S[t] += S[t + off];
        __syncthreads();
    }
    if (t == 0) bsum[b] = S[0];
}
__global__ void k_scan2(int* __restrict__ bsum) {   // 1 block, 256 thr
    __shared__ int S[256];
    int t = threadIdx.x;
    int v = (t < NB) ? bsum[t] : 0;
    S[t] = v;
    __syncthreads();
    for (int off = 1; off < 256; off <<= 1) {
        int x = (t >= off) ? S[t - off] : 0;
        __syncthreads();
        S[t] += x;
        __syncthreads();
    }
    if (t < NB) bsum[t] = S[t] - v;                 // exclusive
}
__global__ void k_scan3(const int* __restrict__ deg, const int* __restrict__ bsum,
                        int* __restrict__ rowptr) {
    __shared__ int S[256];
    int b = blockIdx.x, t = threadIdx.x;
    int i = b * 256 + t;
    int v = (i < NN) ? deg[i] : 0;
    S[t] = v;
    __syncthreads();
    for (int off = 1; off < 256; off <<= 1) {
        int x = (t >= off) ? S[t - off] : 0;
        __syncthreads();
        S[t] += x;
        __syncthreads();
    }
    if (i < NN) rowptr[i] = bsum[b] + S[t] - v;
    if (i == NN - 1) rowptr[NN] = bsum[b] + S[t];   // == NE
}

__global__ void k_fill(const int* __restrict__ src, const int* __restrict__ dst,
                       const int* __restrict__ rowptr, int* __restrict__ cursor,
                       int* __restrict__ colidx) {
    int e = blockIdx.x * 256 + threadIdx.x;
    if (e >= NE) return;
    int d = dst[e];
    int p = atomicAdd(&cursor[d], 1);
    colidx[rowptr[d] + p] = src[e];
}

// pre-swizzle 8 weight matrices into MFMA B-fragment order:
// Wsw[m*16384 + ((nt*4+ks)*64 + lane)*8 + j]
//   = W_m[ks*32 + (lane>>4)*8 + j][nt*16 + (lane&15)]   (bf16)
__global__ void k_swz(const void* __restrict__ w1, const void* __restrict__ w2,
                      u16* __restrict__ Wsw, const int* __restrict__ flag) {
    int t = blockIdx.x * 256 + threadIdx.x;   // 8*16384 = 131072
    if (t >= 8 * 16384) return;
    int m    = t >> 14;
    int idx  = t & 16383;
    int nt   = idx >> 11;
    int ks   = (idx >> 9) & 3;
    int lane = (idx >> 3) & 63;
    int j    = idx & 7;
    int row = ks * 32 + (lane >> 4) * 8 + j;
    int col = nt * 16 + (lane & 15);
    const void* src = (m < 4) ? w1 : w2;
    size_t off = (size_t)(m & 3) * DD * DD + (size_t)row * DD + col;
    Wsw[t] = f2bf(ldf(src, off, *flag));
}

// h0 = vw[feat] + vb + deg_emb[min(deg,1000)] -> B (bf16)
__global__ void k_init(const int* __restrict__ feat, const int* __restrict__ deg,
                       const void* __restrict__ vw, const void* __restrict__ vb,
                       const void* __restrict__ demb, u16* __restrict__ B,
                       const int* __restrict__ flag) {
    int t = blockIdx.x * 256 + threadIdx.x;
    if (t >= NN * DD) return;
    int n = t >> 7, c = t & 127;
    int isbf = *flag;
    int f = feat[n] % FIXED_DIM;
    int dg = min(deg[n], 1000);
    B[t] = f2bf(ldf(vw, (size_t)f * DD + c, isbf)
              + ldf(vb, c, isbf)
              + ldf(demb, (size_t)dg * DD + c, isbf));
}

// GIN aggregation with fused h-recompute, bf16 out:
//   f(x) = AFF ? relu(a[c]*x + b[c]) : x   (a,b from prev layer's BN2 stats)
//   Agg[n] = f(B[n]) + sum_{j in row n} f(B[colidx[j]])
// wave = 1 row, lane = 2 cols; 4-way unrolled neighbor loop (order preserved).
template <bool AFF>
__global__ __launch_bounds__(256, 8) void k_aggr(
        const u16* __restrict__ B, const int* __restrict__ rowptr,
        const int* __restrict__ colidx,
        const float* __restrict__ gIn, const float* __restrict__ bIn,
        const float* __restrict__ sIn, const float* __restrict__ qIn,
        u16* __restrict__ Agg) {
    int n = blockIdx.x * 4 + (threadIdx.x >> 6);
    if (n >= NN) return;
    int c = (threadIdx.x & 63) * 2;
    float a0 = 1.f, b0 = 0.f, a1 = 1.f, b1 = 0.f;
    if (AFF) {
        float inv = 1.0f / (float)NN;
        float mu0 = sIn[c] * inv, mu1 = sIn[c + 1] * inv;
        float v0 = fmaxf(qIn[c] * inv - mu0 * mu0, 0.f);
        float v1 = fmaxf(qIn[c + 1] * inv - mu1 * mu1, 0.f);
        a0 = gIn[c] * rsqrtf(v0 + BN_EPS);
        a1 = gIn[c + 1] * rsqrtf(v1 + BN_EPS);
        b0 = bIn[c] - a0 * mu0;
        b1 = bIn[c + 1] - a1 * mu1;
    }
    u32 w = *(const u32*)&B[(size_t)n * DD + c];
    float x0 = bf2f((u16)(w & 0xFFFF)), x1 = bf2f((u16)(w >> 16));
    float s0 = AFF ? fmaxf(fmaf(a0, x0, b0), 0.f) : x0;
    float s1 = AFF ? fmaxf(fmaf(a1, x1, b1), 0.f) : x1;
    int lo = rowptr[n], hi = rowptr[n + 1];
    int j = lo;
    for (; j + 4 <= hi; j += 4) {
        int m0 = colidx[j], m1 = colidx[j + 1];
        int m2 = colidx[j + 2], m3 = colidx[j + 3];
        u32 w0 = *(const u32*)&B[(size_t)m0 * DD + c];
        u32 w1v = *(const u32*)&B[(size_t)m1 * DD + c];
        u32 w2v = *(const u32*)&B[(size_t)m2 * DD + c];
        u32 w3v = *(const u32*)&B[(size_t)m3 * DD + c];
        float y;
        y = bf2f((u16)(w0 & 0xFFFF)); s0 += AFF ? fmaxf(fmaf(a0, y, b0), 0.f) : y;
        y = bf2f((u16)(w0 >> 16));    s1 += AFF ? fmaxf(fmaf(a1, y, b1), 0.f) : y;
        y = bf2f((u16)(w1v & 0xFFFF)); s0 += AFF ? fmaxf(fmaf(a0, y, b0), 0.f) : y;
        y = bf2f((u16)(w1v >> 16));    s1 += AFF ? fmaxf(fmaf(a1, y, b1), 0.f) : y;
        y = bf2f((u16)(w2v & 0xFFFF)); s0 += AFF ? fmaxf(fmaf(a0, y, b0), 0.f) : y;
        y = bf2f((u16)(w2v >> 16));    s1 += AFF ? fmaxf(fmaf(a1, y, b1), 0.f) : y;
        y = bf2f((u16)(w3v & 0xFFFF)); s0 += AFF ? fmaxf(fmaf(a0, y, b0), 0.f) : y;
        y = bf2f((u16)(w3v >> 16));    s1 += AFF ? fmaxf(fmaf(a1, y, b1), 0.f) : y;
    }
    for (; j < hi; j++) {
        int m = colidx[j];
        w = *(const u32*)&B[(size_t)m * DD + c];
        x0 = bf2f((u16)(w & 0xFFFF)); x1 = bf2f((u16)(w >> 16));
        s0 += AFF ? fmaxf(fmaf(a0, x0, b0), 0.f) : x0;
        s1 += AFF ? fmaxf(fmaf(a1, x1, b1), 0.f) : x1;
    }
    *(u32*)&Agg[(size_t)n * DD + c] = ((u32)f2bf(s1) << 16) | (u32)f2bf(s0);
}

// ---- MFMA GEMM, 128 rows x 128 cols per block (391 blocks) ----
// Out = f(In) @ W + bias; f = AFF ? relu(aff*x+b) : id.
// IN16: bf16 input (pure-copy staging); else fp32 (round once at staging).
// Wave w owns rows w*32..w*32+31 (2 M-tiles); 64 MFMAs/wave.
// LDS: Wl 32K + At 34.8K + affS 1K = 68.6 KB -> 2 blocks/CU.
// Red buffers alias At (dead after MFMA loop). In-place safe (block-local rows).
template <bool IN16, bool OUT16, bool AFF>
__global__ __launch_bounds__(256, 2) void k_gemm(
        const void* In, const u16* __restrict__ Wsw,
        const float* __restrict__ bias,
        const float* __restrict__ gIn, const float* __restrict__ bIn,
        const float* __restrict__ sIn, const float* __restrict__ qIn,
        void* Out, float* __restrict__ ssum, float* __restrict__ ssq,
        int nRows) {
    __shared__ u16 Wl[16384];          // 32 KB swizzled W
    __shared__ u16 At[128 * 136];      // 34.8 KB bf16 A-tile, pitch 136
    __shared__ float affS[256];        // 1 KB
    float* RedS = (float*)At;          // alias At after MFMA loop
    float* RedQ = RedS + 512;
    const int t = threadIdx.x;
    const int row0 = blockIdx.x * 128;

    if (AFF) {
        if (t < 128) {
            float inv = 1.0f / (float)NN;
            float mu = sIn[t] * inv;
            float var = fmaxf(qIn[t] * inv - mu * mu, 0.f);
            float a = gIn[t] * rsqrtf(var + BN_EPS);
            affS[t] = a;
            affS[128 + t] = bIn[t] - a * mu;
        }
        __syncthreads();
    }

    // stage swizzled W: 2048 uint4
    {
        const uint4* s = (const uint4*)Wsw;
        uint4* d = (uint4*)Wl;
        #pragma unroll
        for (int i = 0; i < 8; i++) d[t + i * 256] = s[t + i * 256];
    }
    // stage A-tile (128 rows)
    if (IN16) {
        for (int i = t; i < 2048; i += 256) {
            int r  = i >> 4;
            int c8 = (i & 15) * 8;
            int gr = row0 + r;
            uint4 v = make_uint4(0u, 0u, 0u, 0u);
            if (gr < nRows) v = *(const uint4*)&((const u16*)In)[(size_t)gr * DD + c8];
            *(uint4*)&At[r * 136 + c8] = v;
        }
    } else {
        for (int i = t; i < 4096; i += 256) {
            int r  = i >> 5;
            int c4 = (i & 31) * 4;
            int gr = row0 + r;
            float4 v = make_float4(0.f, 0.f, 0.f, 0.f);
            if (gr < nRows) {
                v = *(const float4*)&((const float*)In)[(size_t)gr * DD + c4];
                if (AFF) {
                    v.x = fmaxf(fmaf(affS[c4 + 0], v.x, affS[128 + c4 + 0]), 0.f);
                    v.y = fmaxf(fmaf(affS[c4 + 1], v.y, affS[128 + c4 + 1]), 0.f);
                    v.z = fmaxf(fmaf(affS[c4 + 2], v.z, affS[128 + c4 + 2]), 0.f);
                    v.w = fmaxf(fmaf(affS[c4 + 3], v.w, affS[128 + c4 + 3]), 0.f);
                }
            }
            ushort4 o;
            o.x = f2bf(v.x); o.y = f2bf(v.y); o.z = f2bf(v.z); o.w = f2bf(v.w);
            *(ushort4*)&At[r * 136 + c4] = o;
        }
    }
    __syncthreads();

    const int w    = t >> 6;
    const int ln   = t & 63;
    const int quad = ln >> 4;
    const int lq   = ln & 15;

    f32x4 acc0[8], acc1[8];
    #pragma unroll
    for (int nt = 0; nt < 8; nt++) {
        acc0[nt] = (f32x4){0.f, 0.f, 0.f, 0.f};
        acc1[nt] = (f32x4){0.f, 0.f, 0.f, 0.f};
    }

    const u16* aRow0 = &At[(w * 32 + lq) * 136 + quad * 8];
    const u16* aRow1 = &At[(w * 32 + 16 + lq) * 136 + quad * 8];
    #pragma unroll
    for (int ks = 0; ks < 4; ks++) {
        bf16x8 a0 = *(const bf16x8*)&aRow0[ks * 32];
        bf16x8 a1 = *(const bf16x8*)&aRow1[ks * 32];
        #pragma unroll
        for (int nt = 0; nt < 8; nt++) {
            bf16x8 b = *(const bf16x8*)&Wl[((nt * 4 + ks) * 64 + ln) * 8];
            acc0[nt] = __builtin_amdgcn_mfma_f32_16x16x32_bf16(a0, b, acc0[nt], 0, 0, 0);
            acc1[nt] = __builtin_amdgcn_mfma_f32_16x16x32_bf16(a1, b, acc1[nt], 0, 0, 0);
        }
    }
    __syncthreads();   // At dead; RedS/RedQ alias it

    // epilogue: D[row=quad*4+r][col=nt*16+lq] for both M-tiles
    const int rb0 = row0 + w * 32 + quad * 4;
    const int rb1 = rb0 + 16;
    #pragma unroll
    for (int nt = 0; nt < 8; nt++) {
        int col = nt * 16 + lq;
        float bv = bias[col];
        float s = 0.f, q = 0.f;
        #pragma unroll
        for (int r = 0; r < 4; r++) {
            int gr = rb0 + r;
            if (gr < nRows) {
                float val = acc0[nt][r] + bv;
                size_t o = (size_t)gr * DD + col;
                if (OUT16) ((u16*)Out)[o] = f2bf(val);
                else       ((float*)Out)[o] = val;
                s += val; q += val * val;
            }
        }
        #pragma unroll
        for (int r = 0; r < 4; r++) {
            int gr = rb1 + r;
            if (gr < nRows) {
                float val = acc1[nt][r] + bv;
                size_t o = (size_t)gr * DD + col;
                if (OUT16) ((u16*)Out)[o] = f2bf(val);
                else       ((float*)Out)[o] = val;
                s += val; q += val * val;
            }
        }
        s += __shfl_xor(s, 16); q += __shfl_xor(q, 16);
        s += __shfl_xor(s, 32); q += __shfl_xor(q, 32);
        if (quad == 0) { RedS[w * 128 + col] = s; RedQ[w * 128 + col] = q; }
    }
    __syncthreads();
    if (t < 128) {
        float s = RedS[t] + RedS[128 + t] + RedS[256 + t] + RedS[384 + t];
        float q = RedQ[t] + RedQ[128 + t] + RedQ[256 + t] + RedQ[384 + t];
        atomicAdd(&ssum[t], s);
        atomicAdd(&ssq[t], q);
    }
}

// final h = relu(a*z2+b) -> A (fp32) + segment-accumulated pool partials.
__global__ __launch_bounds__(256, 4) void k_update2(
        const u16* __restrict__ Bz,
        const float* __restrict__ gIn, const float* __restrict__ bIn,
        const float* __restrict__ sIn, const float* __restrict__ qIn,
        const int* __restrict__ batch, float* __restrict__ A,
        float* __restrict__ gsum) {
    const int t = threadIdx.x;
    const int c = t & 127;
    const int half = t >> 7;           // rows half + 2i
    const int r0 = blockIdx.x * 64;
    float inv = 1.0f / (float)NN;
    float mu = sIn[c] * inv;
    float var = fmaxf(qIn[c] * inv - mu * mu, 0.f);
    float a = gIn[c] * rsqrtf(var + BN_EPS);
    float bb = bIn[c] - a * mu;
    float acc = 0.f;
    int curg = -1;
    for (int i = 0; i < 32; i++) {
        int r = r0 + half + 2 * i;
        if (r >= NN) break;
        int gg = batch[r];
        if (gg != curg) {
            if (curg >= 0) atomicAdd(&gsum[(size_t)curg * DD + c], acc);
            acc = 0.f; curg = gg;
        }
        float v = fmaxf(fmaf(a, bf2f(Bz[(size_t)r * DD + c]), bb), 0.f);
        A[(size_t)r * DD + c] = v;
        acc += v;
    }
    if (curg >= 0) atomicAdd(&gsum[(size_t)curg * DD + c], acc);
}

__global__ void k_pool2(const float* __restrict__ gsum, const int* __restrict__ goff,
                        float* __restrict__ out) {
    int t = blockIdx.x * 256 + threadIdx.x;   // G*DD exact
    int g = t >> 7;
    float cnt = fmaxf((float)(goff[g + 1] - goff[g]), 1.0f);
    out[t] = gsum[t] / cnt;
}

extern "C" void kernel_launch(void* const* d_in, const int* in_sizes, int n_in,
                              void* d_out, int out_size, void* d_ws, size_t ws_size,
                              hipStream_t stream) {
    const int* feat  = (const int*)d_in[0];
    const int* ei    = (const int*)d_in[1];
    const int* batch = (const int*)d_in[2];
    const void* vw   = d_in[3];
    const void* vb   = d_in[4];
    const void* demb = d_in[5];
    const void* w1   = d_in[6];
    const void* b1   = d_in[7];
    const void* g1   = d_in[8];
    const void* be1  = d_in[9];
    const void* w2   = d_in[10];
    const void* b2   = d_in[11];
    const void* g2   = d_in[12];
    const void* be2  = d_in[13];

    const int* src = ei;
    const int* dst = ei + NE;
    const size_t ND = (size_t)NN * DD;

    // ---- workspace layout (~28.4 MB; fill profile shows ws ≈ 256 MB) ----
    float* pc     = (float*)d_ws;            // 3072: b1,b2,g1,be1,g2,be2
    int*   flag   = (int*)(pc + 3072);       // 64
    float* stats  = (float*)(flag + 64);     // 2048 [zero from here...]
    float* gsum   = stats + 2048;            // 8192
    int*   deg    = (int*)(gsum + 8192);     // NN
    int*   cursor = deg + NN;                // NN   [...to here]
    int*   bsum   = cursor + NN;             // 256
    int*   goff   = bsum + 256;              // 128 (65 used)
    int*   rowptr = goff + 128;              // NN+64
    int*   colidx = rowptr + NN + 64;        // NE
    u16*   Wsw    = (u16*)(colidx + NE);     // 8*16384 u16
    u16*   B      = Wsw + 8 * 16384;         // ND bf16
    u16*   Agg16  = B + ND;                  // ND bf16

    float* b1c  = pc;
    float* b2c  = pc + 512;
    float* g1c  = pc + 1024;
    float* be1c = pc + 1536;
    float* g2c  = pc + 2048;
    float* be2c = pc + 2560;
    float* sum1 = stats;          // [NL][128]
    float* sq1  = stats + 512;
    float* sum2 = stats + 1024;
    float* sq2  = stats + 1536;

    float* outw = (float*)d_out;             // [0, NG*DD): graph_feature
    float* A    = outw + (size_t)NG * DD;    // h region: fp32 z1 scratch, final h

    const int zwords = 2048 + 8192 + NN + NN;   // stats, gsum, deg, cursor
    const int gridND = (int)((ND + 255) / 256);
    const int gemmBlocks = (NN + 127) / 128;    // 391
    const int aggrBlocks = (NN + 3) / 4;        // 12500

    k_pre<<<2 + (zwords + 255) / 256, 256, 0, stream>>>(vb, flag, batch, goff,
                                                        stats, zwords);
    k_cvt6<<<(6 * NL * DD + 255) / 256, 256, 0, stream>>>(b1, b2, g1, be1, g2, be2, pc, flag);
    k_swz<<<(8 * 16384) / 256, 256, 0, stream>>>(w1, w2, Wsw, flag);
    k_deg<<<(NE + 255) / 256, 256, 0, stream>>>(dst, deg);
    k_scan1<<<NB, 256, 0, stream>>>(deg, bsum);
    k_scan2<<<1, 256, 0, stream>>>(bsum);
    k_scan3<<<NB, 256, 0, stream>>>(deg, bsum, rowptr);
    k_fill<<<(NE + 255) / 256, 256, 0, stream>>>(src, dst, rowptr, cursor, colidx);
    k_init<<<gridND, 256, 0, stream>>>(feat, deg, vw, vb, demb, B, flag);

    for (int l = 0; l < NL; l++) {
        const u16* W1l = Wsw + (size_t)l * 16384;
        const u16* W2l = Wsw + (size_t)(4 + l) * 16384;
        if (l == 0) {
            k_aggr<false><<<aggrBlocks, 256, 0, stream>>>(
                B, rowptr, colidx, nullptr, nullptr, nullptr, nullptr, Agg16);
        } else {
            k_aggr<true><<<aggrBlocks, 256, 0, stream>>>(
                B, rowptr, colidx, g2c + (l - 1) * 128, be2c + (l - 1) * 128,
                sum2 + (l - 1) * 128, sq2 + (l - 1) * 128, Agg16);
        }
        // GEMM1: Agg16 (bf16) -> A (fp32 z1)
        k_gemm<true, false, false><<<gemmBlocks, 256, 0, stream>>>(
            Agg16, W1l, b1c + l * 128, nullptr, nullptr, nullptr, nullptr,
            A, sum1 + l * 128, sq1 + l * 128, NN);
        // GEMM2: A (fp32 z1) -> B (bf16 z2), affine from BN1 stats
        k_gemm<false, true, true><<<gemmBlocks, 256, 0, stream>>>(
            A, W2l, b2c + l * 128, g1c + l * 128, be1c + l * 128,
            sum1 + l * 128, sq1 + l * 128,
            B, sum2 + l * 128, sq2 + l * 128, NN);
    }
    k_update2<<<(NN + 63) / 64, 256, 0, stream>>>(
        B, g2c + 3 * 128, be2c + 3 * 128, sum2 + 3 * 128, sq2 + 3 * 128,
        batch, A, gsum);
    k_pool2<<<(NG * DD + 255) / 256, 256, 0, stream>>>(gsum, goff, outw);
}